// Round 1
// baseline (440.956 us; speedup 1.0000x reference)
//
#include <hip/hip_runtime.h>
#include <math.h>

#define H 1024
#define V 50257
#define L 4096
#define LOGITS_BLOCKS ((V + 15) / 16)   // 3142, 16 rows per block

__device__ __forceinline__ float wave_sum(float v) {
    #pragma unroll
    for (int off = 32; off; off >>= 1) v += __shfl_down(v, off);
    return v;
}

// online log-sum-exp merge: (m,s) <- merge((m,s),(m2,s2)), guarded for -inf
__device__ __forceinline__ void lse_merge(float& m, float& s, float m2, float s2) {
    if (m2 == -INFINITY) return;
    if (m == -INFINITY) { m = m2; s = s2; return; }
    float nm = fmaxf(m, m2);
    s = s * expf(m - nm) + s2 * expf(m2 - nm);
    m = nm;
}

// 1) e[l] = h_all[l]·Wh + s_prev·Ws + align_b   (wave per row)
__global__ void k_scores(const float* __restrict__ h_all, const float* __restrict__ s_prev,
                         const float* __restrict__ align_W, const float* __restrict__ align_b,
                         float* __restrict__ e) {
    int wave = threadIdx.x >> 6, lane = threadIdx.x & 63;
    int l = blockIdx.x * 4 + wave;
    const float* hrow = h_all + (size_t)l * H;
    const float* Wh = align_W;
    const float* Ws = align_W + H;
    float acc = 0.f;
    #pragma unroll
    for (int it = 0; it < 4; ++it) {
        int k = it * 256 + lane * 4;
        float4 h4 = *(const float4*)(hrow + k);
        float4 w4 = *(const float4*)(Wh + k);
        float4 s4 = *(const float4*)(s_prev + k);
        float4 v4 = *(const float4*)(Ws + k);
        acc += h4.x * w4.x + h4.y * w4.y + h4.z * w4.z + h4.w * w4.w;
        acc += s4.x * v4.x + s4.y * v4.y + s4.z * v4.z + s4.w * v4.w;
    }
    acc = wave_sum(acc);
    if (lane == 0) e[l] = acc + align_b[0];
}

// 2) a = softmax(e), single block of 1024 threads (4 elems/thread); also zero c
__global__ void k_softmax(const float* __restrict__ e, float* __restrict__ a_ws,
                          float* __restrict__ a_out, float* __restrict__ c_ws) {
    __shared__ float redm[16];
    __shared__ float reds[16];
    int tid = threadIdx.x;
    int lane = tid & 63, wave = tid >> 6;
    c_ws[tid] = 0.f;
    float v[4];
    float m = -INFINITY;
    #pragma unroll
    for (int i = 0; i < 4; ++i) { v[i] = e[tid + i * 1024]; m = fmaxf(m, v[i]); }
    #pragma unroll
    for (int off = 32; off; off >>= 1) m = fmaxf(m, __shfl_down(m, off));
    if (lane == 0) redm[wave] = m;
    __syncthreads();
    if (tid == 0) {
        float mm = redm[0];
        for (int w = 1; w < 16; ++w) mm = fmaxf(mm, redm[w]);
        redm[0] = mm;
    }
    __syncthreads();
    m = redm[0];
    float s = 0.f;
    #pragma unroll
    for (int i = 0; i < 4; ++i) { v[i] = expf(v[i] - m); s += v[i]; }
    s = wave_sum(s);
    if (lane == 0) reds[wave] = s;
    __syncthreads();
    if (tid == 0) {
        float ss = 0.f;
        for (int w = 0; w < 16; ++w) ss += reds[w];
        reds[0] = ss;
    }
    __syncthreads();
    float inv = 1.f / reds[0];
    #pragma unroll
    for (int i = 0; i < 4; ++i) {
        float av = v[i] * inv;
        a_ws[tid + i * 1024] = av;
        a_out[tid + i * 1024] = av;
    }
}

// 3) c[j] += sum_l a[l]*h_all[l][j], 16 rows per block, coalesced, atomic combine
__global__ void k_context(const float* __restrict__ h_all, const float* __restrict__ a,
                          float* __restrict__ c) {
    int j = threadIdx.x;           // 0..1023 = column
    int l0 = blockIdx.x * 16;
    float acc = 0.f;
    #pragma unroll
    for (int l = l0; l < l0 + 16; ++l)
        acc += a[l] * h_all[(size_t)l * H + j];
    atomicAdd(c + j, acc);
}

// 4) x[i] = new_W[i,:] · [emb ‖ c] + new_b[i]   (wave per row, dot over 2048)
__global__ void k_xvec(const float* __restrict__ new_W, const float* __restrict__ new_b,
                       const float* __restrict__ emb_W, const int* __restrict__ y,
                       const float* __restrict__ c, float* __restrict__ x) {
    int wave = threadIdx.x >> 6, lane = threadIdx.x & 63;
    int i = blockIdx.x * 4 + wave;
    const float* row = new_W + (size_t)i * (2 * H);
    const float* emb = emb_W + (size_t)y[0] * H;
    float acc = 0.f;
    #pragma unroll
    for (int it = 0; it < 8; ++it) {
        int k = it * 256 + lane * 4;
        float4 w4 = *(const float4*)(row + k);
        float4 v4 = (k < H) ? *(const float4*)(emb + k) : *(const float4*)(c + (k - H));
        acc += w4.x * v4.x + w4.y * v4.y + w4.z * v4.z + w4.w * v4.w;
    }
    acc = wave_sum(acc);
    if (lane == 0) x[i] = acc + new_b[i];
}

// 5) fused GRU: block per output i, 6 waves = 6 row-dots, thread 0 applies gates
__global__ void k_gru(const float* __restrict__ W_ih, const float* __restrict__ b_ih,
                      const float* __restrict__ W_hh, const float* __restrict__ b_hh,
                      const float* __restrict__ x, const float* __restrict__ s_prev,
                      float* __restrict__ h_ws, float* __restrict__ h_out) {
    __shared__ float dots[6];
    int wave = threadIdx.x >> 6, lane = threadIdx.x & 63;
    int i = blockIdx.x;
    int g = wave % 3;
    const float* row;
    const float* vec;
    if (wave < 3) { row = W_ih + (size_t)(g * H + i) * H; vec = x; }
    else          { row = W_hh + (size_t)(g * H + i) * H; vec = s_prev; }
    float acc = 0.f;
    #pragma unroll
    for (int it = 0; it < 4; ++it) {
        int k = it * 256 + lane * 4;
        float4 w4 = *(const float4*)(row + k);
        float4 v4 = *(const float4*)(vec + k);
        acc += w4.x * v4.x + w4.y * v4.y + w4.z * v4.z + w4.w * v4.w;
    }
    acc = wave_sum(acc);
    if (lane == 0) dots[wave] = acc;
    __syncthreads();
    if (threadIdx.x == 0) {
        float ir  = dots[0] + b_ih[i];
        float iz  = dots[1] + b_ih[H + i];
        float in_ = dots[2] + b_ih[2 * H + i];
        float hr  = dots[3] + b_hh[i];
        float hz  = dots[4] + b_hh[H + i];
        float hn  = dots[5] + b_hh[2 * H + i];
        float r = 1.f / (1.f + expf(-(ir + hr)));
        float z = 1.f / (1.f + expf(-(iz + hz)));
        float n = tanhf(in_ + r * hn);
        float h = (1.f - z) * n + z * s_prev[i];
        h_ws[i]  = h;
        h_out[i] = h;
    }
}

// 6) logits[v] = out_W[v,:]·h + out_b[v]; per-block online (m,s) pair for LSE
__global__ void k_logits(const float* __restrict__ out_W, const float* __restrict__ out_b,
                         const float* __restrict__ h, float* __restrict__ logits,
                         float2* __restrict__ pairs) {
    __shared__ float sh_h[H];
    __shared__ float2 wpair[4];
    for (int k = threadIdx.x; k < H; k += 256) sh_h[k] = h[k];
    __syncthreads();
    int wave = threadIdx.x >> 6, lane = threadIdx.x & 63;
    float m = -INFINITY, s = 0.f;
    #pragma unroll
    for (int rr = 0; rr < 4; ++rr) {
        int v = blockIdx.x * 16 + wave * 4 + rr;
        if (v >= V) continue;   // uniform within a wave
        const float* row = out_W + (size_t)v * H;
        float acc = 0.f;
        #pragma unroll
        for (int it = 0; it < 4; ++it) {
            int k = it * 256 + lane * 4;
            float4 w4 = *(const float4*)(row + k);
            float4 h4 = *(const float4*)(sh_h + k);
            acc += w4.x * h4.x + w4.y * h4.y + w4.z * h4.z + w4.w * h4.w;
        }
        acc = wave_sum(acc);
        if (lane == 0) {
            float logit = acc + out_b[v];
            logits[v] = logit;
            lse_merge(m, s, logit, 1.0f);
        }
    }
    if (lane == 0) wpair[wave] = make_float2(m, s);
    __syncthreads();
    if (threadIdx.x == 0) {
        float M = wpair[0].x, S = wpair[0].y;
        for (int w = 1; w < 4; ++w) lse_merge(M, S, wpair[w].x, wpair[w].y);
        pairs[blockIdx.x] = make_float2(M, S);
    }
}

// 7) combine all block pairs -> ms[0]=M, ms[1]=log(S)   (single block)
__global__ void k_combine(const float2* __restrict__ pairs, int n, float* __restrict__ ms) {
    __shared__ float redm[16];
    __shared__ float reds[16];
    int tid = threadIdx.x, lane = tid & 63, wave = tid >> 6;
    float m = -INFINITY, s = 0.f;
    for (int i = tid; i < n; i += 1024) {
        float2 p = pairs[i];
        lse_merge(m, s, p.x, p.y);
    }
    #pragma unroll
    for (int off = 32; off; off >>= 1) {
        float m2 = __shfl_down(m, off);
        float s2 = __shfl_down(s, off);
        lse_merge(m, s, m2, s2);
    }
    if (lane == 0) { redm[wave] = m; reds[wave] = s; }
    __syncthreads();
    if (tid == 0) {
        float M = redm[0], S = reds[0];
        for (int w = 1; w < 16; ++w) lse_merge(M, S, redm[w], reds[w]);
        ms[0] = M;
        ms[1] = logf(S);
    }
}

// 8) logp[v] = logit[v] - M - log(S), in place
__global__ void k_finalize(float* __restrict__ logits, const float* __restrict__ ms) {
    int v = blockIdx.x * 256 + threadIdx.x;
    if (v < V) logits[v] = logits[v] - ms[0] - ms[1];
}

extern "C" void kernel_launch(void* const* d_in, const int* in_sizes, int n_in,
                              void* d_out, int out_size, void* d_ws, size_t ws_size,
                              hipStream_t stream) {
    const int*   y       = (const int*)d_in[0];
    const float* s_prev  = (const float*)d_in[1];
    const float* h_all   = (const float*)d_in[2];
    const float* emb_W   = (const float*)d_in[3];
    const float* align_W = (const float*)d_in[4];
    const float* align_b = (const float*)d_in[5];
    const float* new_W   = (const float*)d_in[6];
    const float* new_b   = (const float*)d_in[7];
    const float* W_ih    = (const float*)d_in[8];
    const float* b_ih    = (const float*)d_in[9];
    const float* W_hh    = (const float*)d_in[10];
    const float* b_hh    = (const float*)d_in[11];
    const float* out_W   = (const float*)d_in[12];
    const float* out_b   = (const float*)d_in[13];

    float* out      = (float*)d_out;
    float* logp_out = out;            // V
    float* h_out    = out + V;        // H
    float* a_out    = out + V + H;    // L

    // workspace layout (floats): e[4096] a[4096] c[1024] x[1024] h[1024] ms[2] pairs[2*LOGITS_BLOCKS]
    float*  ws       = (float*)d_ws;
    float*  ws_e     = ws;
    float*  ws_a     = ws + 4096;
    float*  ws_c     = ws + 8192;
    float*  ws_x     = ws + 9216;
    float*  ws_h     = ws + 10240;
    float*  ws_ms    = ws + 11264;
    float2* ws_pairs = (float2*)(ws + 11266);   // byte offset 45064, 8B aligned

    k_scores  <<<L / 4, 256, 0, stream>>>(h_all, s_prev, align_W, align_b, ws_e);
    k_softmax <<<1, 1024, 0, stream>>>(ws_e, ws_a, a_out, ws_c);
    k_context <<<L / 16, 1024, 0, stream>>>(h_all, ws_a, ws_c);
    k_xvec    <<<H / 4, 256, 0, stream>>>(new_W, new_b, emb_W, y, ws_c, ws_x);
    k_gru     <<<H, 384, 0, stream>>>(W_ih, b_ih, W_hh, b_hh, ws_x, s_prev, ws_h, h_out);
    k_logits  <<<LOGITS_BLOCKS, 256, 0, stream>>>(out_W, out_b, ws_h, logp_out, ws_pairs);
    k_combine <<<1, 1024, 0, stream>>>(ws_pairs, LOGITS_BLOCKS, ws_ms);
    k_finalize<<<(V + 255) / 256, 256, 0, stream>>>(logp_out, ws_ms);
}